// Round 2
// baseline (994.140 us; speedup 1.0000x reference)
//
#include <hip/hip_runtime.h>

// ---- problem constants (match reference) ----
#define NTOK   16384      // B*T
#define DMODEL 1024
#define FFF    4096
#define NEXP   8
#define CAP    2560       // int(1.25 * NTOK / NEXP)
#define NASSIGN (NTOK*2)  // top-2

typedef __bf16 bf16x8 __attribute__((ext_vector_type(8)));
typedef float  f32x4  __attribute__((ext_vector_type(4)));
typedef unsigned short u16x8 __attribute__((ext_vector_type(8)));

__device__ __forceinline__ unsigned short f2bf(float f) {
    unsigned int u = __float_as_uint(f);
    u = u + 0x7FFFu + ((u >> 16) & 1u);   // RNE
    return (unsigned short)(u >> 16);
}
__device__ __forceinline__ float bf2f(unsigned short s) {
    return __uint_as_float(((unsigned int)s) << 16);
}

// ======== fused prologue: router (blocks 0..4095) + w1/w2 transpose ========
// router: one wave per token, fp32 logits -> softmax -> top2
__device__ void router_body(int rb, const float* __restrict__ x,
                            const float* __restrict__ wr,
                            const float* __restrict__ br,
                            int* __restrict__ topi,
                            float* __restrict__ topv) {
    int t    = rb * 4 + (threadIdx.x >> 6);
    int lane = threadIdx.x & 63;
    const float4* xr4 = reinterpret_cast<const float4*>(x + (size_t)t * DMODEL);
    float a[8] = {0.f,0.f,0.f,0.f,0.f,0.f,0.f,0.f};
    #pragma unroll
    for (int i = lane; i < DMODEL/4; i += 64) {
        float4 xv = xr4[i];
        const float* w = wr + i * 32;
        #pragma unroll
        for (int e = 0; e < 8; e++) a[e] = fmaf(xv.x, w[e],      a[e]);
        #pragma unroll
        for (int e = 0; e < 8; e++) a[e] = fmaf(xv.y, w[8 + e],  a[e]);
        #pragma unroll
        for (int e = 0; e < 8; e++) a[e] = fmaf(xv.z, w[16 + e], a[e]);
        #pragma unroll
        for (int e = 0; e < 8; e++) a[e] = fmaf(xv.w, w[24 + e], a[e]);
    }
    #pragma unroll
    for (int off = 32; off > 0; off >>= 1) {
        #pragma unroll
        for (int e = 0; e < 8; e++) a[e] += __shfl_xor(a[e], off, 64);
    }
    if (lane == 0) {
        float l[8], g[8];
        float mx = -1e30f;
        #pragma unroll
        for (int e = 0; e < 8; e++) { l[e] = a[e] + br[e]; mx = fmaxf(mx, l[e]); }
        float s = 0.f;
        #pragma unroll
        for (int e = 0; e < 8; e++) { g[e] = expf(l[e] - mx); s += g[e]; }
        float inv = 1.f / s;
        #pragma unroll
        for (int e = 0; e < 8; e++) g[e] *= inv;
        float v1 = -1.f, v2 = -1.f; int i1 = 0, i2 = 0;
        #pragma unroll
        for (int e = 0; e < 8; e++) {
            float v = g[e];
            if (v > v1)      { v2 = v1; i2 = i1; v1 = v; i1 = e; }
            else if (v > v2) { v2 = v; i2 = e; }
        }
        topi[t*2]   = i1; topi[t*2+1] = i2;
        topv[t*2]   = v1; topv[t*2+1] = v2;
    }
}

// transpose fp32 [R][C] tile (r0,c0) -> bf16 [C][R]; 64x64, pad 65 (2-way max)
__device__ void transpose_body(const float* __restrict__ src,
                               unsigned short* __restrict__ dst,
                               int R, int C, int r0, int c0) {
    __shared__ float tile[64 * 65];
    int t = threadIdx.x;
    int lr4 = (t & 15) * 4;
    #pragma unroll
    for (int s = 0; s < 4; s++) {
        int r = (t >> 4) + s * 16;
        float4 v = *reinterpret_cast<const float4*>(&src[(size_t)(r0 + r) * C + c0 + lr4]);
        float* tr = &tile[r * 65 + lr4];
        tr[0] = v.x; tr[1] = v.y; tr[2] = v.z; tr[3] = v.w;
    }
    __syncthreads();
    int j = t & 7;
    int ccb = t >> 3;
    #pragma unroll
    for (int s = 0; s < 2; s++) {
        int cc = ccb + s * 32;
        u16x8 o;
        #pragma unroll
        for (int k = 0; k < 8; k++) o[k] = f2bf(tile[(j * 8 + k) * 65 + cc]);
        *reinterpret_cast<u16x8*>(&dst[(size_t)(c0 + cc) * R + r0 + j * 8]) = o;
    }
}

__global__ void prologue_kernel(const float* __restrict__ x,
                                const float* __restrict__ wr,
                                const float* __restrict__ br,
                                const float* __restrict__ w1,
                                const float* __restrict__ w2,
                                int* __restrict__ topi,
                                float* __restrict__ topv,
                                unsigned short* __restrict__ w1t,
                                unsigned short* __restrict__ w2t) {
    int id = blockIdx.x;
    if (id < NTOK/4) {
        router_body(id, x, wr, br, topi, topv);
    } else if (id < NTOK/4 + 8192) {
        // w1 [e][D][F] -> w1t [e][F][D]; 1024 blocks/expert (64 x-chunks, 16 y)
        int q = id - NTOK/4;
        int e = q >> 10, t = q & 1023;
        int bx = t & 63, by = t >> 6;
        transpose_body(w1 + (size_t)e * DMODEL * FFF,
                       w1t + (size_t)e * DMODEL * FFF,
                       DMODEL, FFF, by * 64, bx * 64);
    } else {
        // w2 [e][F][D] -> w2t [e][D][F]; 1024 blocks/expert (16 x-chunks, 64 y)
        int q = id - NTOK/4 - 8192;
        int e = q >> 10, t = q & 1023;
        int bx = t & 15, by = t >> 4;
        transpose_body(w2 + (size_t)e * DMODEL * FFF,
                       w2t + (size_t)e * DMODEL * FFF,
                       FFF, DMODEL, by * 64, bx * 64);
    }
}

// ------- scan: arrival-order positions per expert (single block) -------
__global__ void scan_kernel(const int* __restrict__ topi,
                            int* __restrict__ pos,
                            int* __restrict__ slot_tok,
                            int* __restrict__ kept) {
    const int APT = NASSIGN / 256;
    int tid = threadIdx.x, lane = tid & 63, w = tid >> 6;
    int base = tid * APT;
    const int4* tp = reinterpret_cast<const int4*>(topi + base);
    int c[8] = {0,0,0,0,0,0,0,0};
    for (int i = 0; i < APT/4; i++) {
        int4 v = tp[i];
        #pragma unroll
        for (int q = 0; q < 8; q++)
            c[q] += (v.x == q) + (v.y == q) + (v.z == q) + (v.w == q);
    }
    int excl[8], wtot[8];
    #pragma unroll
    for (int e = 0; e < 8; e++) {
        int s = c[e];
        for (int off = 1; off < 64; off <<= 1) {
            int n = __shfl_up(s, off, 64);
            if (lane >= off) s += n;
        }
        excl[e] = s - c[e];
        wtot[e] = __shfl(s, 63, 64);
    }
    __shared__ int woff[4][8];
    if (lane == 0) {
        #pragma unroll
        for (int e = 0; e < 8; e++) woff[w][e] = wtot[e];
    }
    __syncthreads();
    if (tid == 0) {
        for (int e = 0; e < 8; e++) {
            int run = 0;
            for (int ww = 0; ww < 4; ww++) { int t0 = woff[ww][e]; woff[ww][e] = run; run += t0; }
            kept[e] = run < CAP ? run : CAP;
        }
    }
    __syncthreads();
    int run[8];
    #pragma unroll
    for (int e = 0; e < 8; e++) run[e] = woff[w][e] + excl[e];
    for (int i = 0; i < APT/4; i++) {
        int4 v = tp[i];
        int ev[4] = {v.x, v.y, v.z, v.w};
        #pragma unroll
        for (int u = 0; u < 4; u++) {
            int a = base + i*4 + u;
            int e = ev[u];
            int p = 0;
            #pragma unroll
            for (int q = 0; q < 8; q++) if (e == q) { p = run[q]; run[q] = p + 1; }
            pos[a] = p;
            if (p < CAP) slot_tok[(size_t)e * CAP + p] = a >> 1;
        }
    }
}

// ------------- dispatch: gather kept tokens -> bf16 [E][CAP][D] -------------
__global__ void dispatch_kernel(const float* __restrict__ x,
                                const int* __restrict__ slot_tok,
                                const int* __restrict__ kept,
                                unsigned short* __restrict__ xb) {
    int row  = blockIdx.x * 4 + (threadIdx.x >> 6);
    int lane = threadIdx.x & 63;
    int e = row / CAP;
    int p = row - e * CAP;
    if (p >= kept[e]) return;           // wave-uniform
    int t = slot_tok[row];
    const float4* src = reinterpret_cast<const float4*>(x + (size_t)t * DMODEL);
    ushort4* dst = reinterpret_cast<ushort4*>(xb + (size_t)row * DMODEL);
    #pragma unroll
    for (int i = lane; i < DMODEL/4; i += 64) {
        float4 v = src[i];
        ushort4 o;
        o.x = f2bf(v.x); o.y = f2bf(v.y); o.z = f2bf(v.z); o.w = f2bf(v.w);
        dst[i] = o;
    }
}

// ============================================================================
// 256x256 8-phase GEMM (T1+T2+T3+T4+T5): C[e][M][N] = A[e][M][K]*Bt[e][N][K]^T
// 512 threads = 8 waves (2M x 4N), per-wave 128x64 output, BK=64.
// LDS 128 KiB: A,B double-buffered [2][256*64] bf16, XOR chunk swizzle.
// A stored group-permuted: phys row = q*64 + half*32 + (row&31); each compute
// phase q reads exactly group q (one contiguous 8 KB global_load_lds region),
// so groups die per-phase and prefetch slots never race:
//   ph0: issue A(t+1).g2,g3   (buf p^1; g2/g3 read finished at t-1 ph2/ph3)
//   ph1: issue B(t+2).b0,b1   (buf p;  all Bs read in ph0 -> reg-cached)
//   ph2: issue B(t+2).b2,b3
//   ph3: issue A(t+2).g0,g1; s_waitcnt vmcnt(6)  (= loads issued after
//        A(t+1).g23 -> tile t+1 fully arrived; never drains to 0 mid-loop)
// NOTE: global_load_lds LDS dest MUST be wave-uniform (HW adds lane*16B);
// per-lane dest pointers risk a waterfall loop / wrong addresses (m104/m108).
// ============================================================================
template<int GELU>
__global__ __launch_bounds__(512, 2)
void gemm_8p(const unsigned short* __restrict__ A,
             const unsigned short* __restrict__ Bt,
             const float* __restrict__ bias,
             unsigned short* __restrict__ C,
             int M, int N, int K) {
    constexpr int BM = 256, BN = 256, BK = 64;
    __shared__ __align__(16) unsigned short As[2][BM * BK];
    __shared__ __align__(16) unsigned short Bs[2][BN * BK];

    const int e = blockIdx.z;
    const int gx = N / BN, gy = M / BM;
    const int nc = gx < 8 ? gx : 8;          // n-chunk width (XCD L2 pinning)
    int id = blockIdx.x;
    const int per_chunk = nc * gy;
    const int chunk = id / per_chunk;
    const int r = id - chunk * per_chunk;
    const int bn = chunk * nc + (r % nc);
    const int bm = r / nc;

    const unsigned short* Ab = A  + (size_t)e * M * K + (size_t)bm * BM * K;
    const unsigned short* Bb = Bt + (size_t)e * N * K + (size_t)bn * BN * K;
    const float* bp = bias + (size_t)e * N;

    const int tid  = threadIdx.x;
    const int lane = tid & 63;
    const int wv   = tid >> 6;
    const int half = wv >> 2;        // A half: rows half*128 ..
    const int wn   = (wv & 3) * 64;  // B col group
    const int lr   = lane & 15;
    const int quad = lane >> 4;

    // staging geometry: one region = 64 LDS rows x 64 cols bf16 = 8 KB = one
    // global_load_lds(16B) by 512 threads. XOR pre-swizzle on the SOURCE so the
    // linear LDS dest ends up swizzled (both-sides rule). LDS dest is the
    // WAVE-UNIFORM base of this wave's 1 KB slice; HW adds lane*16B.
    const int sprow = tid >> 3;                  // row within region (0..63)
    const int schunk = (tid & 7) ^ (sprow & 7);  // source 16B chunk

    auto stageA = [&](int pb, int kt, int g) {
        int lrow = g * 32 + (sprow & 31) + ((sprow >> 5) << 7);
        __builtin_amdgcn_global_load_lds(
            (const __attribute__((address_space(1))) unsigned int*)
                (Ab + (size_t)lrow * K + kt * BK + schunk * 8),
            (__attribute__((address_space(3))) unsigned int*)
                (&As[pb][g * 4096 + wv * 512]),
            16, 0, 0);
    };
    auto stageB = [&](int pb, int kt, int h2) {
        int row = h2 * 64 + sprow;
        __builtin_amdgcn_global_load_lds(
            (const __attribute__((address_space(1))) unsigned int*)
                (Bb + (size_t)row * K + kt * BK + schunk * 8),
            (__attribute__((address_space(3))) unsigned int*)
                (&Bs[pb][h2 * 4096 + wv * 512]),
            16, 0, 0);
    };

    f32x4 acc[8][4] = {};
    const int NT = K / BK;

    // ---- prologue: tile0 fully + tile1 {B all, A g0,g1} in flight ----
    stageA(0, 0, 0); stageA(0, 0, 1); stageA(0, 0, 2); stageA(0, 0, 3);
    stageB(0, 0, 0); stageB(0, 0, 1); stageB(0, 0, 2); stageB(0, 0, 3);
    if (NT > 1) {
        stageB(1, 1, 0); stageB(1, 1, 1); stageB(1, 1, 2); stageB(1, 1, 3);
        stageA(1, 1, 0); stageA(1, 1, 1);
        asm volatile("s_waitcnt vmcnt(6)" ::: "memory");   // tile0 arrived
    } else {
        asm volatile("s_waitcnt vmcnt(0)" ::: "memory");
    }
    __builtin_amdgcn_s_barrier();

    for (int t = 0; t < NT; ++t) {
        const int p = t & 1;
        const unsigned short* Asp = &As[p][0];
        const unsigned short* Bsp = &Bs[p][0];
        bf16x8 bfr[4][2];
        #pragma unroll
        for (int q = 0; q < 4; ++q) {
            // ---- ds-load register subtile ----
            bf16x8 af[2][2];
            #pragma unroll
            for (int i2 = 0; i2 < 2; ++i2) {
                #pragma unroll
                for (int ks = 0; ks < 2; ++ks) {
                    int pr = q * 64 + half * 32 + i2 * 16 + lr;
                    int cp = (ks * 4 + quad) ^ (pr & 7);
                    af[i2][ks] = *reinterpret_cast<const bf16x8*>(&Asp[pr * 64 + cp * 8]);
                }
            }
            if (q == 0) {
                #pragma unroll
                for (int jf = 0; jf < 4; ++jf) {
                    #pragma unroll
                    for (int ks = 0; ks < 2; ++ks) {
                        int pr = wn + jf * 16 + lr;
                        int cp = (ks * 4 + quad) ^ (pr & 7);
                        bfr[jf][ks] = *reinterpret_cast<const bf16x8*>(&Bsp[pr * 64 + cp * 8]);
                    }
                }
            }
            // ---- stage slot (counted prefetch; regions proven dead) ----
            if (q == 0)      { if (t + 1 < NT) { stageA(p ^ 1, t + 1, 2); stageA(p ^ 1, t + 1, 3); } }
            else if (q == 1) { if (t + 2 < NT) { stageB(p, t + 2, 0); stageB(p, t + 2, 1); } }
            else if (q == 2) { if (t + 2 < NT) { stageB(p, t + 2, 2); stageB(p, t + 2, 3); } }
            else             { if (t + 2 < NT) { stageA(p, t + 2, 0); stageA(p, t + 2, 1); } }

            __builtin_amdgcn_s_barrier();
            asm volatile("s_waitcnt lgkmcnt(0)" ::: "memory");
            __builtin_amdgcn_s_setprio(1);
            #pragma unroll
            for (int ks = 0; ks < 2; ++ks) {
                #pragma unroll
                for (int i2 = 0; i2 < 2; ++i2) {
                    #pragma unroll
                    for (int jf = 0; jf < 4; ++jf) {
                        acc[q * 2 + i2][jf] = __builtin_amdgcn_mfma_f32_16x16x32_bf16(
                            af[i2][ks], bfr[jf][ks], acc[q * 2 + i2][jf], 0, 0, 0);
                    }
                }
            }
            __builtin_amdgcn_s_setprio(0);
            if (q == 3) {
                if (t + 2 < NT)      asm volatile("s_waitcnt vmcnt(6)" ::: "memory");
                else if (t + 1 < NT) asm volatile("s_waitcnt vmcnt(0)" ::: "memory");
            }
            __builtin_amdgcn_s_barrier();
        }
    }

    // ---- epilogue ----
    size_t cbase = (size_t)e * M * N + (size_t)bm * BM * N + (size_t)bn * BN;
    float bv[4];
    #pragma unroll
    for (int jf = 0; jf < 4; ++jf) bv[jf] = bp[bn * BN + wn + jf * 16 + lr];
    #pragma unroll
    for (int m = 0; m < 8; ++m) {
        #pragma unroll
        for (int rr = 0; rr < 4; ++rr) {
            int row = half * 128 + (m >> 1) * 32 + (m & 1) * 16 + quad * 4 + rr;
            #pragma unroll
            for (int jf = 0; jf < 4; ++jf) {
                int col = wn + jf * 16 + lr;
                float v = acc[m][jf][rr] + bv[jf];
                if (GELU) v = 0.5f * v * (1.f + erff(v * 0.70710678118654752440f));
                C[cbase + (size_t)row * N + col] = f2bf(v);
            }
        }
    }
}

// ------------- combine: weighted sum of expert outputs, normalize -------------
__global__ void combine_kernel(const int* __restrict__ topi,
                               const float* __restrict__ topv,
                               const int* __restrict__ pos,
                               const unsigned short* __restrict__ out2,
                               float* __restrict__ y) {
    int t    = blockIdx.x * 4 + (threadIdx.x >> 6);
    int lane = threadIdx.x & 63;
    int e0 = topi[t*2],   e1 = topi[t*2+1];
    float g0 = topv[t*2], g1 = topv[t*2+1];
    int p0 = pos[t*2],    p1 = pos[t*2+1];
    float w0 = (p0 < CAP) ? g0 : 0.f;
    float w1 = (p1 < CAP) ? g1 : 0.f;
    float wsum = w0 + w1;
    float scale = (wsum > 0.f) ? 1.f / fmaxf(wsum, 1e-6f) : 0.f;
    int q0 = p0 < CAP ? p0 : CAP - 1;
    int q1 = p1 < CAP ? p1 : CAP - 1;
    const ushort4* o0 = reinterpret_cast<const ushort4*>(out2 + ((size_t)e0 * CAP + q0) * DMODEL);
    const ushort4* o1 = reinterpret_cast<const ushort4*>(out2 + ((size_t)e1 * CAP + q1) * DMODEL);
    float4* dst = reinterpret_cast<float4*>(y + (size_t)t * DMODEL);
    #pragma unroll
    for (int i = lane; i < DMODEL/4; i += 64) {
        ushort4 a = o0[i], b = o1[i];
        float4 r;
        r.x = (w0 * bf2f(a.x) + w1 * bf2f(b.x)) * scale;
        r.y = (w0 * bf2f(a.y) + w1 * bf2f(b.y)) * scale;
        r.z = (w0 * bf2f(a.z) + w1 * bf2f(b.z)) * scale;
        r.w = (w0 * bf2f(a.w) + w1 * bf2f(b.w)) * scale;
        dst[i] = r;
    }
}

extern "C" void kernel_launch(void* const* d_in, const int* in_sizes, int n_in,
                              void* d_out, int out_size, void* d_ws, size_t ws_size,
                              hipStream_t stream) {
    (void)in_sizes; (void)n_in; (void)out_size; (void)ws_size;
    const float* x        = (const float*)d_in[0];
    const float* w_router = (const float*)d_in[1];
    const float* b_router = (const float*)d_in[2];
    const float* w1       = (const float*)d_in[3];
    const float* b1       = (const float*)d_in[4];
    const float* w2       = (const float*)d_in[5];
    const float* b2       = (const float*)d_in[6];
    float* y = (float*)d_out;

    char* ws = (char*)d_ws;
    size_t off = 0;
    auto alloc = [&](size_t n) { char* p = ws + off; off = (off + n + 255) & ~(size_t)255; return p; };
    int*   topi     = (int*)  alloc((size_t)NASSIGN * 4);
    float* topv     = (float*)alloc((size_t)NASSIGN * 4);
    int*   pos      = (int*)  alloc((size_t)NASSIGN * 4);
    int*   slot_tok = (int*)  alloc((size_t)NEXP * CAP * 4);
    int*   kept     = (int*)  alloc(8 * 4);
    unsigned short* w1t = (unsigned short*)alloc((size_t)NEXP * DMODEL * FFF * 2);
    unsigned short* w2t = (unsigned short*)alloc((size_t)NEXP * DMODEL * FFF * 2);
    unsigned short* xb  = (unsigned short*)alloc((size_t)NEXP * CAP * DMODEL * 2);
    unsigned short* h   = (unsigned short*)alloc((size_t)NEXP * CAP * FFF * 2);
    unsigned short* out2 = w1t;  // alias: w1t is dead after GEMM1

    prologue_kernel<<<NTOK/4 + 16384, 256, 0, stream>>>(
        x, w_router, b_router, w1, w2, topi, topv, w1t, w2t);
    scan_kernel<<<1, 256, 0, stream>>>(topi, pos, slot_tok, kept);
    dispatch_kernel<<<NEXP*CAP/4, 256, 0, stream>>>(x, slot_tok, kept, xb);
    gemm_8p<1><<<dim3((FFF/256)*(CAP/256), 1, NEXP), 512, 0, stream>>>(xb, w1t, b1, h, CAP, FFF, DMODEL);
    gemm_8p<0><<<dim3((DMODEL/256)*(CAP/256), 1, NEXP), 512, 0, stream>>>(h, w2t, b2, out2, CAP, DMODEL, FFF);
    combine_kernel<<<NTOK/4, 256, 0, stream>>>(topi, topv, pos, out2, y);
}

// Round 3
// 949.430 us; speedup vs baseline: 1.0471x; 1.0471x over previous
//
#include <hip/hip_runtime.h>

// ---- problem constants (match reference) ----
#define NTOK   16384      // B*T
#define DMODEL 1024
#define FFF    4096
#define NEXP   8
#define CAP    2560       // int(1.25 * NTOK / NEXP)
#define NASSIGN (NTOK*2)  // top-2

typedef __bf16 bf16x8 __attribute__((ext_vector_type(8)));
typedef float  f32x4  __attribute__((ext_vector_type(4)));
typedef unsigned short u16x8 __attribute__((ext_vector_type(8)));

template<int V> struct IC { static constexpr int value = V; };

__device__ __forceinline__ unsigned short f2bf(float f) {
    unsigned int u = __float_as_uint(f);
    u = u + 0x7FFFu + ((u >> 16) & 1u);   // RNE
    return (unsigned short)(u >> 16);
}
__device__ __forceinline__ float bf2f(unsigned short s) {
    return __uint_as_float(((unsigned int)s) << 16);
}

// ======== fused prologue: router (blocks 0..4095) + w1/w2 transpose ========
__device__ void router_body(int rb, const float* __restrict__ x,
                            const float* __restrict__ wr,
                            const float* __restrict__ br,
                            int* __restrict__ topi,
                            float* __restrict__ topv) {
    int t    = rb * 4 + (threadIdx.x >> 6);
    int lane = threadIdx.x & 63;
    const float4* xr4 = reinterpret_cast<const float4*>(x + (size_t)t * DMODEL);
    float a[8] = {0.f,0.f,0.f,0.f,0.f,0.f,0.f,0.f};
    #pragma unroll
    for (int i = lane; i < DMODEL/4; i += 64) {
        float4 xv = xr4[i];
        const float* w = wr + i * 32;
        #pragma unroll
        for (int e = 0; e < 8; e++) a[e] = fmaf(xv.x, w[e],      a[e]);
        #pragma unroll
        for (int e = 0; e < 8; e++) a[e] = fmaf(xv.y, w[8 + e],  a[e]);
        #pragma unroll
        for (int e = 0; e < 8; e++) a[e] = fmaf(xv.z, w[16 + e], a[e]);
        #pragma unroll
        for (int e = 0; e < 8; e++) a[e] = fmaf(xv.w, w[24 + e], a[e]);
    }
    #pragma unroll
    for (int off = 32; off > 0; off >>= 1) {
        #pragma unroll
        for (int e = 0; e < 8; e++) a[e] += __shfl_xor(a[e], off, 64);
    }
    if (lane == 0) {
        float l[8], g[8];
        float mx = -1e30f;
        #pragma unroll
        for (int e = 0; e < 8; e++) { l[e] = a[e] + br[e]; mx = fmaxf(mx, l[e]); }
        float s = 0.f;
        #pragma unroll
        for (int e = 0; e < 8; e++) { g[e] = expf(l[e] - mx); s += g[e]; }
        float inv = 1.f / s;
        #pragma unroll
        for (int e = 0; e < 8; e++) g[e] *= inv;
        float v1 = -1.f, v2 = -1.f; int i1 = 0, i2 = 0;
        #pragma unroll
        for (int e = 0; e < 8; e++) {
            float v = g[e];
            if (v > v1)      { v2 = v1; i2 = i1; v1 = v; i1 = e; }
            else if (v > v2) { v2 = v; i2 = e; }
        }
        topi[t*2]   = i1; topi[t*2+1] = i2;
        topv[t*2]   = v1; topv[t*2+1] = v2;
    }
}

// transpose fp32 [R][C] tile (r0,c0) -> bf16 [C][R]; 64x64, pad 65 (2-way max)
__device__ void transpose_body(const float* __restrict__ src,
                               unsigned short* __restrict__ dst,
                               int R, int C, int r0, int c0) {
    __shared__ float tile[64 * 65];
    int t = threadIdx.x;
    int lr4 = (t & 15) * 4;
    #pragma unroll
    for (int s = 0; s < 4; s++) {
        int r = (t >> 4) + s * 16;
        float4 v = *reinterpret_cast<const float4*>(&src[(size_t)(r0 + r) * C + c0 + lr4]);
        float* tr = &tile[r * 65 + lr4];
        tr[0] = v.x; tr[1] = v.y; tr[2] = v.z; tr[3] = v.w;
    }
    __syncthreads();
    int j = t & 7;
    int ccb = t >> 3;
    #pragma unroll
    for (int s = 0; s < 2; s++) {
        int cc = ccb + s * 32;
        u16x8 o;
        #pragma unroll
        for (int k = 0; k < 8; k++) o[k] = f2bf(tile[(j * 8 + k) * 65 + cc]);
        *reinterpret_cast<u16x8*>(&dst[(size_t)(c0 + cc) * R + r0 + j * 8]) = o;
    }
}

__global__ void prologue_kernel(const float* __restrict__ x,
                                const float* __restrict__ wr,
                                const float* __restrict__ br,
                                const float* __restrict__ w1,
                                const float* __restrict__ w2,
                                int* __restrict__ topi,
                                float* __restrict__ topv,
                                unsigned short* __restrict__ w1t,
                                unsigned short* __restrict__ w2t) {
    int id = blockIdx.x;
    if (id < NTOK/4) {
        router_body(id, x, wr, br, topi, topv);
    } else if (id < NTOK/4 + 8192) {
        int q = id - NTOK/4;
        int e = q >> 10, t = q & 1023;
        int bx = t & 63, by = t >> 6;
        transpose_body(w1 + (size_t)e * DMODEL * FFF,
                       w1t + (size_t)e * DMODEL * FFF,
                       DMODEL, FFF, by * 64, bx * 64);
    } else {
        int q = id - NTOK/4 - 8192;
        int e = q >> 10, t = q & 1023;
        int bx = t & 15, by = t >> 4;
        transpose_body(w2 + (size_t)e * DMODEL * FFF,
                       w2t + (size_t)e * DMODEL * FFF,
                       FFF, DMODEL, by * 64, bx * 64);
    }
}

// ------- scan: arrival-order positions per expert (single block) -------
__global__ void scan_kernel(const int* __restrict__ topi,
                            int* __restrict__ pos,
                            int* __restrict__ slot_tok,
                            int* __restrict__ kept) {
    const int APT = NASSIGN / 256;
    int tid = threadIdx.x, lane = tid & 63, w = tid >> 6;
    int base = tid * APT;
    const int4* tp = reinterpret_cast<const int4*>(topi + base);
    int c[8] = {0,0,0,0,0,0,0,0};
    for (int i = 0; i < APT/4; i++) {
        int4 v = tp[i];
        #pragma unroll
        for (int q = 0; q < 8; q++)
            c[q] += (v.x == q) + (v.y == q) + (v.z == q) + (v.w == q);
    }
    int excl[8], wtot[8];
    #pragma unroll
    for (int e = 0; e < 8; e++) {
        int s = c[e];
        for (int off = 1; off < 64; off <<= 1) {
            int n = __shfl_up(s, off, 64);
            if (lane >= off) s += n;
        }
        excl[e] = s - c[e];
        wtot[e] = __shfl(s, 63, 64);
    }
    __shared__ int woff[4][8];
    if (lane == 0) {
        #pragma unroll
        for (int e = 0; e < 8; e++) woff[w][e] = wtot[e];
    }
    __syncthreads();
    if (tid == 0) {
        for (int e = 0; e < 8; e++) {
            int run = 0;
            for (int ww = 0; ww < 4; ww++) { int t0 = woff[ww][e]; woff[ww][e] = run; run += t0; }
            kept[e] = run < CAP ? run : CAP;
        }
    }
    __syncthreads();
    int run[8];
    #pragma unroll
    for (int e = 0; e < 8; e++) run[e] = woff[w][e] + excl[e];
    for (int i = 0; i < APT/4; i++) {
        int4 v = tp[i];
        int ev[4] = {v.x, v.y, v.z, v.w};
        #pragma unroll
        for (int u = 0; u < 4; u++) {
            int a = base + i*4 + u;
            int e = ev[u];
            int p = 0;
            #pragma unroll
            for (int q = 0; q < 8; q++) if (e == q) { p = run[q]; run[q] = p + 1; }
            pos[a] = p;
            if (p < CAP) slot_tok[(size_t)e * CAP + p] = a >> 1;
        }
    }
}

// ------------- dispatch: gather kept tokens -> bf16 [E][CAP][D] -------------
__global__ void dispatch_kernel(const float* __restrict__ x,
                                const int* __restrict__ slot_tok,
                                const int* __restrict__ kept,
                                unsigned short* __restrict__ xb) {
    int row  = blockIdx.x * 4 + (threadIdx.x >> 6);
    int lane = threadIdx.x & 63;
    int e = row / CAP;
    int p = row - e * CAP;
    if (p >= kept[e]) return;           // wave-uniform
    int t = slot_tok[row];
    const float4* src = reinterpret_cast<const float4*>(x + (size_t)t * DMODEL);
    ushort4* dst = reinterpret_cast<ushort4*>(xb + (size_t)row * DMODEL);
    #pragma unroll
    for (int i = lane; i < DMODEL/4; i += 64) {
        float4 v = src[i];
        ushort4 o;
        o.x = f2bf(v.x); o.y = f2bf(v.y); o.z = f2bf(v.z); o.w = f2bf(v.w);
        dst[i] = o;
    }
}

// ============================================================================
// 256x256 8-phase GEMM (T1+T2+T3+T4+T5): C[e][M][N] = A[e][M][K]*Bt[e][N][K]^T
// 512 threads = 8 waves (2M x 4N), per-wave 128x64 output, BK=64.
// LDS 128 KiB: A,B double-buffered [2][256*64] bf16, XOR chunk swizzle.
// A stored group-permuted: phys row = q*64 + half*32 + (row&31); each compute
// phase q reads exactly group q, so regions die per-phase and prefetch slots
// never race:
//   ph0: issue A(t+1).g2,g3   ph1: B(t+2).b0,b1   ph2: B(t+2).b2,b3
//   ph3: A(t+2).g0,g1 + s_waitcnt vmcnt(6) (never 0 mid-loop)
// R2 change: all per-lane LDS read offsets + global staging bases precomputed
// ONCE (HK "prefill_swizzled_offsets"); t-loop unrolled x2 so the dbuf base is
// compile-time -> ds_read_b128 [reg+imm], ~0 VALU per phase (was ~60, VALU 42%).
// ============================================================================
template<int GELU>
__global__ __launch_bounds__(512, 2)
void gemm_8p(const unsigned short* __restrict__ A,
             const unsigned short* __restrict__ Bt,
             const float* __restrict__ bias,
             unsigned short* __restrict__ C,
             int M, int N, int K) {
    constexpr int BM = 256, BN = 256, BK = 64;
    __shared__ __align__(16) unsigned short As[2][BM * BK];
    __shared__ __align__(16) unsigned short Bs[2][BN * BK];

    const int e = blockIdx.z;
    const int gx = N / BN, gy = M / BM;
    const int nc = gx < 8 ? gx : 8;          // n-chunk width (XCD L2 pinning)
    int id = blockIdx.x;
    const int per_chunk = nc * gy;
    const int chunk = id / per_chunk;
    const int r = id - chunk * per_chunk;
    const int bn = chunk * nc + (r % nc);
    const int bm = r / nc;

    const unsigned short* Ab = A  + (size_t)e * M * K + (size_t)bm * BM * K;
    const unsigned short* Bb = Bt + (size_t)e * N * K + (size_t)bn * BN * K;
    const float* bp = bias + (size_t)e * N;

    const int tid  = threadIdx.x;
    const int lane = tid & 63;
    const int wv   = tid >> 6;
    const int half = wv >> 2;        // A half: rows half*128 ..
    const int wn   = (wv & 3) * 64;  // B col group
    const int lr   = lane & 15;
    const int quad = lane >> 4;

    // ---- precomputed per-lane LDS read offsets (elements) ----
    // fragment row pr always has pr&7 == lr&7 (all other terms are mult of 8),
    // so the swizzle chunk (ks*4+quad)^(pr&7) is phase-invariant; ks=1 is ^32.
    const int ksx   = (quad ^ (lr & 7)) * 8;
    const int aoff0 = (half * 32 + lr) * 64 + ksx;
    const int boff0 = ((wv & 3) * 64 + lr) * 64 + ksx;
    const unsigned short* a00 = &As[0][aoff0];
    const unsigned short* a01 = &As[0][aoff0 ^ 32];
    const unsigned short* a10 = &As[1][aoff0];
    const unsigned short* a11 = &As[1][aoff0 ^ 32];
    const unsigned short* b00 = &Bs[0][boff0];
    const unsigned short* b01 = &Bs[0][boff0 ^ 32];
    const unsigned short* b10 = &Bs[1][boff0];
    const unsigned short* b11 = &Bs[1][boff0 ^ 32];

    // ---- precomputed per-lane global staging bases ----
    // one region = 64 rows x 64 cols bf16 = 8 KB = one global_load_lds(16B) by
    // 512 threads; XOR pre-swizzle on the SOURCE (both-sides rule); LDS dest is
    // the wave-uniform base of this wave's 1 KB slice (HW adds lane*16B).
    const int sprow  = tid >> 3;                 // row within region (0..63)
    const int schunk = (tid & 7) ^ (sprow & 7);  // source 16B chunk
    const size_t K32 = (size_t)32 * K;
    const unsigned short* gA0 = Ab + (size_t)((sprow & 31) + ((sprow >> 5) << 7)) * K + schunk * 8;
    const unsigned short* gB0 = Bb + (size_t)sprow * K + schunk * 8;

    auto stageA = [&](int pb, int kt, int g) {
        __builtin_amdgcn_global_load_lds(
            (const __attribute__((address_space(1))) unsigned int*)
                (gA0 + (size_t)g * K32 + kt * BK),
            (__attribute__((address_space(3))) unsigned int*)
                (&As[pb][g * 4096 + wv * 512]),
            16, 0, 0);
    };
    auto stageB = [&](int pb, int kt, int h2) {
        __builtin_amdgcn_global_load_lds(
            (const __attribute__((address_space(1))) unsigned int*)
                (gB0 + (size_t)h2 * 2 * K32 + kt * BK),
            (__attribute__((address_space(3))) unsigned int*)
                (&Bs[pb][h2 * 4096 + wv * 512]),
            16, 0, 0);
    };

    f32x4 acc[8][4] = {};
    const int NT = K / BK;     // 16 (K=1024) or 64 (K=4096) -> always even

    // ---- prologue: tile0 fully + tile1 {B all, A g0,g1} in flight ----
    stageA(0, 0, 0); stageA(0, 0, 1); stageA(0, 0, 2); stageA(0, 0, 3);
    stageB(0, 0, 0); stageB(0, 0, 1); stageB(0, 0, 2); stageB(0, 0, 3);
    stageB(1, 1, 0); stageB(1, 1, 1); stageB(1, 1, 2); stageB(1, 1, 3);
    stageA(1, 1, 0); stageA(1, 1, 1);
    asm volatile("s_waitcnt vmcnt(6)" ::: "memory");   // tile0 arrived
    __builtin_amdgcn_s_barrier();

    auto tile = [&](auto pc, int tt) {
        constexpr int P = decltype(pc)::value;
        const unsigned short* aK0 = P ? a10 : a00;
        const unsigned short* aK1 = P ? a11 : a01;
        const unsigned short* bK0 = P ? b10 : b00;
        const unsigned short* bK1 = P ? b11 : b01;
        bf16x8 bfr[4][2];
        #pragma unroll
        for (int q = 0; q < 4; ++q) {
            bf16x8 af[2][2];
            #pragma unroll
            for (int i2 = 0; i2 < 2; ++i2) {
                af[i2][0] = *reinterpret_cast<const bf16x8*>(aK0 + q * 4096 + i2 * 1024);
                af[i2][1] = *reinterpret_cast<const bf16x8*>(aK1 + q * 4096 + i2 * 1024);
            }
            if (q == 0) {
                #pragma unroll
                for (int jf = 0; jf < 4; ++jf) {
                    bfr[jf][0] = *reinterpret_cast<const bf16x8*>(bK0 + jf * 1024);
                    bfr[jf][1] = *reinterpret_cast<const bf16x8*>(bK1 + jf * 1024);
                }
            }
            // ---- stage slot (counted prefetch; regions proven dead) ----
            if (q == 0)      { if (tt + 1 < NT) { stageA(P ^ 1, tt + 1, 2); stageA(P ^ 1, tt + 1, 3); } }
            else if (q == 1) { if (tt + 2 < NT) { stageB(P, tt + 2, 0); stageB(P, tt + 2, 1); } }
            else if (q == 2) { if (tt + 2 < NT) { stageB(P, tt + 2, 2); stageB(P, tt + 2, 3); } }
            else             { if (tt + 2 < NT) { stageA(P, tt + 2, 0); stageA(P, tt + 2, 1); } }

            __builtin_amdgcn_s_barrier();
            asm volatile("s_waitcnt lgkmcnt(0)" ::: "memory");
            __builtin_amdgcn_s_setprio(1);
            #pragma unroll
            for (int ks = 0; ks < 2; ++ks) {
                #pragma unroll
                for (int i2 = 0; i2 < 2; ++i2) {
                    #pragma unroll
                    for (int jf = 0; jf < 4; ++jf) {
                        acc[q * 2 + i2][jf] = __builtin_amdgcn_mfma_f32_16x16x32_bf16(
                            af[i2][ks], bfr[jf][ks], acc[q * 2 + i2][jf], 0, 0, 0);
                    }
                }
            }
            __builtin_amdgcn_s_setprio(0);
            if (q == 3) {
                if (tt + 2 < NT)      asm volatile("s_waitcnt vmcnt(6)" ::: "memory");
                else if (tt + 1 < NT) asm volatile("s_waitcnt vmcnt(0)" ::: "memory");
            }
            __builtin_amdgcn_s_barrier();
        }
    };

    for (int t = 0; t < NT; t += 2) {
        tile(IC<0>{}, t);
        tile(IC<1>{}, t + 1);
    }

    // ---- epilogue ----
    size_t cbase = (size_t)e * M * N + (size_t)bm * BM * N + (size_t)bn * BN;
    float bv[4];
    #pragma unroll
    for (int jf = 0; jf < 4; ++jf) bv[jf] = bp[bn * BN + wn + jf * 16 + lr];
    #pragma unroll
    for (int m = 0; m < 8; ++m) {
        #pragma unroll
        for (int rr = 0; rr < 4; ++rr) {
            int row = half * 128 + (m >> 1) * 32 + (m & 1) * 16 + quad * 4 + rr;
            #pragma unroll
            for (int jf = 0; jf < 4; ++jf) {
                int col = wn + jf * 16 + lr;
                float v = acc[m][jf][rr] + bv[jf];
                if (GELU) v = 0.5f * v * (1.f + erff(v * 0.70710678118654752440f));
                C[cbase + (size_t)row * N + col] = f2bf(v);
            }
        }
    }
}

// ------------- combine: weighted sum of expert outputs, normalize -------------
__global__ void combine_kernel(const int* __restrict__ topi,
                               const float* __restrict__ topv,
                               const int* __restrict__ pos,
                               const unsigned short* __restrict__ out2,
                               float* __restrict__ y) {
    int t    = blockIdx.x * 4 + (threadIdx.x >> 6);
    int lane = threadIdx.x & 63;
    int e0 = topi[t*2],   e1 = topi[t*2+1];
    float g0 = topv[t*2], g1 = topv[t*2+1];
    int p0 = pos[t*2],    p1 = pos[t*2+1];
    float w0 = (p0 < CAP) ? g0 : 0.f;
    float w1 = (p1 < CAP) ? g1 : 0.f;
    float wsum = w0 + w1;
    float scale = (wsum > 0.f) ? 1.f / fmaxf(wsum, 1e-6f) : 0.f;
    int q0 = p0 < CAP ? p0 : CAP - 1;
    int q1 = p1 < CAP ? p1 : CAP - 1;
    const ushort4* o0 = reinterpret_cast<const ushort4*>(out2 + ((size_t)e0 * CAP + q0) * DMODEL);
    const ushort4* o1 = reinterpret_cast<const ushort4*>(out2 + ((size_t)e1 * CAP + q1) * DMODEL);
    float4* dst = reinterpret_cast<float4*>(y + (size_t)t * DMODEL);
    #pragma unroll
    for (int i = lane; i < DMODEL/4; i += 64) {
        ushort4 a = o0[i], b = o1[i];
        float4 r;
        r.x = (w0 * bf2f(a.x) + w1 * bf2f(b.x)) * scale;
        r.y = (w0 * bf2f(a.y) + w1 * bf2f(b.y)) * scale;
        r.z = (w0 * bf2f(a.z) + w1 * bf2f(b.z)) * scale;
        r.w = (w0 * bf2f(a.w) + w1 * bf2f(b.w)) * scale;
        dst[i] = r;
    }
}

extern "C" void kernel_launch(void* const* d_in, const int* in_sizes, int n_in,
                              void* d_out, int out_size, void* d_ws, size_t ws_size,
                              hipStream_t stream) {
    (void)in_sizes; (void)n_in; (void)out_size; (void)ws_size;
    const float* x        = (const float*)d_in[0];
    const float* w_router = (const float*)d_in[1];
    const float* b_router = (const float*)d_in[2];
    const float* w1       = (const float*)d_in[3];
    const float* b1       = (const float*)d_in[4];
    const float* w2       = (const float*)d_in[5];
    const float* b2       = (const float*)d_in[6];
    float* y = (float*)d_out;

    char* ws = (char*)d_ws;
    size_t off = 0;
    auto alloc = [&](size_t n) { char* p = ws + off; off = (off + n + 255) & ~(size_t)255; return p; };
    int*   topi     = (int*)  alloc((size_t)NASSIGN * 4);
    float* topv     = (float*)alloc((size_t)NASSIGN * 4);
    int*   pos      = (int*)  alloc((size_t)NASSIGN * 4);
    int*   slot_tok = (int*)  alloc((size_t)NEXP * CAP * 4);
    int*   kept     = (int*)  alloc(8 * 4);
    unsigned short* w1t = (unsigned short*)alloc((size_t)NEXP * DMODEL * FFF * 2);
    unsigned short* w2t = (unsigned short*)alloc((size_t)NEXP * DMODEL * FFF * 2);
    unsigned short* xb  = (unsigned short*)alloc((size_t)NEXP * CAP * DMODEL * 2);
    unsigned short* h   = (unsigned short*)alloc((size_t)NEXP * CAP * FFF * 2);
    unsigned short* out2 = w1t;  // alias: w1t is dead after GEMM1

    prologue_kernel<<<NTOK/4 + 16384, 256, 0, stream>>>(
        x, w_router, b_router, w1, w2, topi, topv, w1t, w2t);
    scan_kernel<<<1, 256, 0, stream>>>(topi, pos, slot_tok, kept);
    dispatch_kernel<<<NEXP*CAP/4, 256, 0, stream>>>(x, slot_tok, kept, xb);
    gemm_8p<1><<<dim3((FFF/256)*(CAP/256), 1, NEXP), 512, 0, stream>>>(xb, w1t, b1, h, CAP, FFF, DMODEL);
    gemm_8p<0><<<dim3((DMODEL/256)*(CAP/256), 1, NEXP), 512, 0, stream>>>(h, w2t, b2, out2, CAP, DMODEL, FFF);
    combine_kernel<<<NTOK/4, 256, 0, stream>>>(topi, topv, pos, out2, y);
}

// Round 4
// 946.315 us; speedup vs baseline: 1.0505x; 1.0033x over previous
//
#include <hip/hip_runtime.h>

// ---- problem constants (match reference) ----
#define NTOK   16384      // B*T
#define DMODEL 1024
#define FFF    4096
#define NEXP   8
#define CAP    2560       // int(1.25 * NTOK / NEXP)
#define NASSIGN (NTOK*2)  // top-2

typedef __bf16 bf16x8 __attribute__((ext_vector_type(8)));
typedef float  f32x4  __attribute__((ext_vector_type(4)));
typedef unsigned short u16x8 __attribute__((ext_vector_type(8)));

template<int V> struct IC { static constexpr int value = V; };

__device__ __forceinline__ unsigned short f2bf(float f) {
    unsigned int u = __float_as_uint(f);
    u = u + 0x7FFFu + ((u >> 16) & 1u);   // RNE
    return (unsigned short)(u >> 16);
}
__device__ __forceinline__ float bf2f(unsigned short s) {
    return __uint_as_float(((unsigned int)s) << 16);
}

// ======== fused prologue: router (blocks 0..4095) + w1/w2 transpose ========
__device__ void router_body(int rb, const float* __restrict__ x,
                            const float* __restrict__ wr,
                            const float* __restrict__ br,
                            int* __restrict__ topi,
                            float* __restrict__ topv) {
    int t    = rb * 4 + (threadIdx.x >> 6);
    int lane = threadIdx.x & 63;
    const float4* xr4 = reinterpret_cast<const float4*>(x + (size_t)t * DMODEL);
    float a[8] = {0.f,0.f,0.f,0.f,0.f,0.f,0.f,0.f};
    #pragma unroll
    for (int i = lane; i < DMODEL/4; i += 64) {
        float4 xv = xr4[i];
        const float* w = wr + i * 32;
        #pragma unroll
        for (int e = 0; e < 8; e++) a[e] = fmaf(xv.x, w[e],      a[e]);
        #pragma unroll
        for (int e = 0; e < 8; e++) a[e] = fmaf(xv.y, w[8 + e],  a[e]);
        #pragma unroll
        for (int e = 0; e < 8; e++) a[e] = fmaf(xv.z, w[16 + e], a[e]);
        #pragma unroll
        for (int e = 0; e < 8; e++) a[e] = fmaf(xv.w, w[24 + e], a[e]);
    }
    #pragma unroll
    for (int off = 32; off > 0; off >>= 1) {
        #pragma unroll
        for (int e = 0; e < 8; e++) a[e] += __shfl_xor(a[e], off, 64);
    }
    if (lane == 0) {
        float l[8], g[8];
        float mx = -1e30f;
        #pragma unroll
        for (int e = 0; e < 8; e++) { l[e] = a[e] + br[e]; mx = fmaxf(mx, l[e]); }
        float s = 0.f;
        #pragma unroll
        for (int e = 0; e < 8; e++) { g[e] = expf(l[e] - mx); s += g[e]; }
        float inv = 1.f / s;
        #pragma unroll
        for (int e = 0; e < 8; e++) g[e] *= inv;
        float v1 = -1.f, v2 = -1.f; int i1 = 0, i2 = 0;
        #pragma unroll
        for (int e = 0; e < 8; e++) {
            float v = g[e];
            if (v > v1)      { v2 = v1; i2 = i1; v1 = v; i1 = e; }
            else if (v > v2) { v2 = v; i2 = e; }
        }
        topi[t*2]   = i1; topi[t*2+1] = i2;
        topv[t*2]   = v1; topv[t*2+1] = v2;
    }
}

// transpose fp32 [R][C] tile (r0,c0) -> bf16 [C][R]; 64x64, pad 65 (2-way max)
__device__ void transpose_body(const float* __restrict__ src,
                               unsigned short* __restrict__ dst,
                               int R, int C, int r0, int c0) {
    __shared__ float tile[64 * 65];
    int t = threadIdx.x;
    int lr4 = (t & 15) * 4;
    #pragma unroll
    for (int s = 0; s < 4; s++) {
        int r = (t >> 4) + s * 16;
        float4 v = *reinterpret_cast<const float4*>(&src[(size_t)(r0 + r) * C + c0 + lr4]);
        float* tr = &tile[r * 65 + lr4];
        tr[0] = v.x; tr[1] = v.y; tr[2] = v.z; tr[3] = v.w;
    }
    __syncthreads();
    int j = t & 7;
    int ccb = t >> 3;
    #pragma unroll
    for (int s = 0; s < 2; s++) {
        int cc = ccb + s * 32;
        u16x8 o;
        #pragma unroll
        for (int k = 0; k < 8; k++) o[k] = f2bf(tile[(j * 8 + k) * 65 + cc]);
        *reinterpret_cast<u16x8*>(&dst[(size_t)(c0 + cc) * R + r0 + j * 8]) = o;
    }
}

__global__ void prologue_kernel(const float* __restrict__ x,
                                const float* __restrict__ wr,
                                const float* __restrict__ br,
                                const float* __restrict__ w1,
                                const float* __restrict__ w2,
                                int* __restrict__ topi,
                                float* __restrict__ topv,
                                unsigned short* __restrict__ w1t,
                                unsigned short* __restrict__ w2t) {
    int id = blockIdx.x;
    if (id < NTOK/4) {
        router_body(id, x, wr, br, topi, topv);
    } else if (id < NTOK/4 + 8192) {
        int q = id - NTOK/4;
        int e = q >> 10, t = q & 1023;
        int bx = t & 63, by = t >> 6;
        transpose_body(w1 + (size_t)e * DMODEL * FFF,
                       w1t + (size_t)e * DMODEL * FFF,
                       DMODEL, FFF, by * 64, bx * 64);
    } else {
        int q = id - NTOK/4 - 8192;
        int e = q >> 10, t = q & 1023;
        int bx = t & 15, by = t >> 4;
        transpose_body(w2 + (size_t)e * DMODEL * FFF,
                       w2t + (size_t)e * DMODEL * FFF,
                       FFF, DMODEL, by * 64, bx * 64);
    }
}

// ------- scan: arrival-order positions per expert (single block) -------
__global__ void scan_kernel(const int* __restrict__ topi,
                            int* __restrict__ pos,
                            int* __restrict__ slot_tok,
                            int* __restrict__ kept) {
    const int APT = NASSIGN / 256;
    int tid = threadIdx.x, lane = tid & 63, w = tid >> 6;
    int base = tid * APT;
    const int4* tp = reinterpret_cast<const int4*>(topi + base);
    int c[8] = {0,0,0,0,0,0,0,0};
    for (int i = 0; i < APT/4; i++) {
        int4 v = tp[i];
        #pragma unroll
        for (int q = 0; q < 8; q++)
            c[q] += (v.x == q) + (v.y == q) + (v.z == q) + (v.w == q);
    }
    int excl[8], wtot[8];
    #pragma unroll
    for (int e = 0; e < 8; e++) {
        int s = c[e];
        for (int off = 1; off < 64; off <<= 1) {
            int n = __shfl_up(s, off, 64);
            if (lane >= off) s += n;
        }
        excl[e] = s - c[e];
        wtot[e] = __shfl(s, 63, 64);
    }
    __shared__ int woff[4][8];
    if (lane == 0) {
        #pragma unroll
        for (int e = 0; e < 8; e++) woff[w][e] = wtot[e];
    }
    __syncthreads();
    if (tid == 0) {
        for (int e = 0; e < 8; e++) {
            int run = 0;
            for (int ww = 0; ww < 4; ww++) { int t0 = woff[ww][e]; woff[ww][e] = run; run += t0; }
            kept[e] = run < CAP ? run : CAP;
        }
    }
    __syncthreads();
    int run[8];
    #pragma unroll
    for (int e = 0; e < 8; e++) run[e] = woff[w][e] + excl[e];
    for (int i = 0; i < APT/4; i++) {
        int4 v = tp[i];
        int ev[4] = {v.x, v.y, v.z, v.w};
        #pragma unroll
        for (int u = 0; u < 4; u++) {
            int a = base + i*4 + u;
            int e = ev[u];
            int p = 0;
            #pragma unroll
            for (int q = 0; q < 8; q++) if (e == q) { p = run[q]; run[q] = p + 1; }
            pos[a] = p;
            if (p < CAP) slot_tok[(size_t)e * CAP + p] = a >> 1;
        }
    }
}

// ------------- dispatch: gather kept tokens -> bf16 [E][CAP][D] -------------
__global__ void dispatch_kernel(const float* __restrict__ x,
                                const int* __restrict__ slot_tok,
                                const int* __restrict__ kept,
                                unsigned short* __restrict__ xb) {
    int row  = blockIdx.x * 4 + (threadIdx.x >> 6);
    int lane = threadIdx.x & 63;
    int e = row / CAP;
    int p = row - e * CAP;
    if (p >= kept[e]) return;           // wave-uniform
    int t = slot_tok[row];
    const float4* src = reinterpret_cast<const float4*>(x + (size_t)t * DMODEL);
    ushort4* dst = reinterpret_cast<ushort4*>(xb + (size_t)row * DMODEL);
    #pragma unroll
    for (int i = lane; i < DMODEL/4; i += 64) {
        float4 v = src[i];
        ushort4 o;
        o.x = f2bf(v.x); o.y = f2bf(v.y); o.z = f2bf(v.z); o.w = f2bf(v.w);
        dst[i] = o;
    }
}

// ============================================================================
// 256x256 8-phase GEMM (used for GEMM1 only, K=1024, 1280 blocks = 5 waves).
// R4 change: grid mapping pins the A/M-panel per XCD (bm = chunk*8 + id%8),
// bn sweeps. A-loads (shallow 3-phase prefetch) become L2-hits; B becomes the
// streamed operand and has 6-7-phase (~1300 cyc) prefetch depth -> HBM latency
// covered by the counted vmcnt(6). Schedule unchanged from R3:
//   ph0: issue A(t+1).g2,g3   ph1: B(t+2).b0,b1   ph2: B(t+2).b2,b3
//   ph3: A(t+2).g0,g1 + s_waitcnt vmcnt(6) (never 0 mid-loop)
// ============================================================================
template<int GELU>
__global__ __launch_bounds__(512, 2)
void gemm_8p(const unsigned short* __restrict__ A,
             const unsigned short* __restrict__ Bt,
             const float* __restrict__ bias,
             unsigned short* __restrict__ C,
             int M, int N, int K) {
    constexpr int BM = 256, BN = 256, BK = 64;
    __shared__ __align__(16) unsigned short As[2][BM * BK];
    __shared__ __align__(16) unsigned short Bs[2][BN * BK];

    const int e = blockIdx.z;
    const int gx = N / BN, gy = M / BM;
    // ---- M-pinned chunking: XCD k <- fixed bm (= chunk*8 + k), bn sweeps ----
    int id = blockIdx.x;
    const int cw = 8 * gx;
    const int chunk = id / cw;
    const int rr0 = id - chunk * cw;
    const int rem = gy - chunk * 8;
    const int mcw = rem < 8 ? rem : 8;
    const int bm = chunk * 8 + rr0 % mcw;
    const int bn = rr0 / mcw;

    const unsigned short* Ab = A  + (size_t)e * M * K + (size_t)bm * BM * K;
    const unsigned short* Bb = Bt + (size_t)e * N * K + (size_t)bn * BN * K;
    const float* bp = bias + (size_t)e * N;

    const int tid  = threadIdx.x;
    const int lane = tid & 63;
    const int wv   = tid >> 6;
    const int half = wv >> 2;        // A half: rows half*128 ..
    const int wn   = (wv & 3) * 64;  // B col group
    const int lr   = lane & 15;
    const int quad = lane >> 4;

    // ---- precomputed per-lane LDS read offsets (elements) ----
    // fragment row pr always has pr&7 == lr&7, so the swizzle chunk
    // (ks*4+quad)^(pr&7) is phase-invariant; ks=1 is ^32.
    const int ksx   = (quad ^ (lr & 7)) * 8;
    const int aoff0 = (half * 32 + lr) * 64 + ksx;
    const int boff0 = ((wv & 3) * 64 + lr) * 64 + ksx;
    const unsigned short* a00 = &As[0][aoff0];
    const unsigned short* a01 = &As[0][aoff0 ^ 32];
    const unsigned short* a10 = &As[1][aoff0];
    const unsigned short* a11 = &As[1][aoff0 ^ 32];
    const unsigned short* b00 = &Bs[0][boff0];
    const unsigned short* b01 = &Bs[0][boff0 ^ 32];
    const unsigned short* b10 = &Bs[1][boff0];
    const unsigned short* b11 = &Bs[1][boff0 ^ 32];

    // ---- precomputed per-lane global staging bases ----
    // one region = 64 rows x 64 cols bf16 = 8 KB = one global_load_lds(16B) by
    // 512 threads; XOR pre-swizzle on the SOURCE (both-sides rule); LDS dest is
    // the wave-uniform base of this wave's 1 KB slice (HW adds lane*16B).
    const int sprow  = tid >> 3;                 // row within region (0..63)
    const int schunk = (tid & 7) ^ (sprow & 7);  // source 16B chunk
    const size_t K32 = (size_t)32 * K;
    const unsigned short* gA0 = Ab + (size_t)((sprow & 31) + ((sprow >> 5) << 7)) * K + schunk * 8;
    const unsigned short* gB0 = Bb + (size_t)sprow * K + schunk * 8;

    auto stageA = [&](int pb, int kt, int g) {
        __builtin_amdgcn_global_load_lds(
            (const __attribute__((address_space(1))) unsigned int*)
                (gA0 + (size_t)g * K32 + kt * BK),
            (__attribute__((address_space(3))) unsigned int*)
                (&As[pb][g * 4096 + wv * 512]),
            16, 0, 0);
    };
    auto stageB = [&](int pb, int kt, int h2) {
        __builtin_amdgcn_global_load_lds(
            (const __attribute__((address_space(1))) unsigned int*)
                (gB0 + (size_t)h2 * 2 * K32 + kt * BK),
            (__attribute__((address_space(3))) unsigned int*)
                (&Bs[pb][h2 * 4096 + wv * 512]),
            16, 0, 0);
    };

    f32x4 acc[8][4] = {};
    const int NT = K / BK;     // 16 for GEMM1 -> always even

    // ---- prologue: tile0 fully + tile1 {B all, A g0,g1} in flight ----
    stageA(0, 0, 0); stageA(0, 0, 1); stageA(0, 0, 2); stageA(0, 0, 3);
    stageB(0, 0, 0); stageB(0, 0, 1); stageB(0, 0, 2); stageB(0, 0, 3);
    stageB(1, 1, 0); stageB(1, 1, 1); stageB(1, 1, 2); stageB(1, 1, 3);
    stageA(1, 1, 0); stageA(1, 1, 1);
    asm volatile("s_waitcnt vmcnt(6)" ::: "memory");   // tile0 arrived
    __builtin_amdgcn_s_barrier();

    auto tile = [&](auto pc, int tt) {
        constexpr int P = decltype(pc)::value;
        const unsigned short* aK0 = P ? a10 : a00;
        const unsigned short* aK1 = P ? a11 : a01;
        const unsigned short* bK0 = P ? b10 : b00;
        const unsigned short* bK1 = P ? b11 : b01;
        bf16x8 bfr[4][2];
        #pragma unroll
        for (int q = 0; q < 4; ++q) {
            bf16x8 af[2][2];
            #pragma unroll
            for (int i2 = 0; i2 < 2; ++i2) {
                af[i2][0] = *reinterpret_cast<const bf16x8*>(aK0 + q * 4096 + i2 * 1024);
                af[i2][1] = *reinterpret_cast<const bf16x8*>(aK1 + q * 4096 + i2 * 1024);
            }
            if (q == 0) {
                #pragma unroll
                for (int jf = 0; jf < 4; ++jf) {
                    bfr[jf][0] = *reinterpret_cast<const bf16x8*>(bK0 + jf * 1024);
                    bfr[jf][1] = *reinterpret_cast<const bf16x8*>(bK1 + jf * 1024);
                }
            }
            // ---- stage slot (counted prefetch; regions proven dead) ----
            if (q == 0)      { if (tt + 1 < NT) { stageA(P ^ 1, tt + 1, 2); stageA(P ^ 1, tt + 1, 3); } }
            else if (q == 1) { if (tt + 2 < NT) { stageB(P, tt + 2, 0); stageB(P, tt + 2, 1); } }
            else if (q == 2) { if (tt + 2 < NT) { stageB(P, tt + 2, 2); stageB(P, tt + 2, 3); } }
            else             { if (tt + 2 < NT) { stageA(P, tt + 2, 0); stageA(P, tt + 2, 1); } }

            __builtin_amdgcn_s_barrier();
            asm volatile("s_waitcnt lgkmcnt(0)" ::: "memory");
            __builtin_amdgcn_s_setprio(1);
            #pragma unroll
            for (int ks = 0; ks < 2; ++ks) {
                #pragma unroll
                for (int i2 = 0; i2 < 2; ++i2) {
                    #pragma unroll
                    for (int jf = 0; jf < 4; ++jf) {
                        acc[q * 2 + i2][jf] = __builtin_amdgcn_mfma_f32_16x16x32_bf16(
                            af[i2][ks], bfr[jf][ks], acc[q * 2 + i2][jf], 0, 0, 0);
                    }
                }
            }
            __builtin_amdgcn_s_setprio(0);
            if (q == 3) {
                if (tt + 2 < NT)      asm volatile("s_waitcnt vmcnt(6)" ::: "memory");
                else if (tt + 1 < NT) asm volatile("s_waitcnt vmcnt(0)" ::: "memory");
            }
            __builtin_amdgcn_s_barrier();
        }
    };

    for (int t = 0; t < NT; t += 2) {
        tile(IC<0>{}, t);
        tile(IC<1>{}, t + 1);
    }

    // ---- epilogue ----
    size_t cbase = (size_t)e * M * N + (size_t)bm * BM * N + (size_t)bn * BN;
    float bv[4];
    #pragma unroll
    for (int jf = 0; jf < 4; ++jf) bv[jf] = bp[bn * BN + wn + jf * 16 + lr];
    #pragma unroll
    for (int m = 0; m < 8; ++m) {
        #pragma unroll
        for (int rr = 0; rr < 4; ++rr) {
            int row = half * 128 + (m >> 1) * 32 + (m & 1) * 16 + quad * 4 + rr;
            #pragma unroll
            for (int jf = 0; jf < 4; ++jf) {
                int col = wn + jf * 16 + lr;
                float v = acc[m][jf][rr] + bv[jf];
                if (GELU) v = 0.5f * v * (1.f + erff(v * 0.70710678118654752440f));
                C[cbase + (size_t)row * N + col] = f2bf(v);
            }
        }
    }
}

// ------------- GEMM (proven R0): C[e][M][N] = A[e][M][K] * Bt[e][N][K]^T -------------
// global_load_lds width=16, XOR chunk swizzle. Block order: per expert, N in
// chunks of 8 tiles with N fastest -> each XCD pins one B-tile in its L2 while
// A streams. grid = dim3(gx*gy, 1, NEXP).
template<int GELU>
__global__ __launch_bounds__(256, 2)
void gemm_bt(const unsigned short* __restrict__ A,
             const unsigned short* __restrict__ Bt,
             const float* __restrict__ bias,
             unsigned short* __restrict__ C,
             int M, int N, int K) {
    constexpr int BM = 128, BN = 128, BK = 64;
    __shared__ unsigned short As[BM * 64];
    __shared__ unsigned short Bs[BN * 64];
    const int e = blockIdx.z;
    const int gx = N / BN, gy = M / BM;
    const int nc = gx < 8 ? gx : 8;          // n-chunk width
    int id = blockIdx.x;
    const int per_chunk = nc * gy;
    const int chunk = id / per_chunk;
    const int r = id - chunk * per_chunk;
    const int bn = chunk * nc + (r % nc);
    const int bm = r / nc;

    const unsigned short* Ab = A  + (size_t)e * M * K + (size_t)bm * BM * K;
    const unsigned short* Bb = Bt + (size_t)e * N * K + (size_t)bn * BN * K;
    const float* bp = bias + (size_t)e * N;
    const int tid  = threadIdx.x;
    const int lane = tid & 63;
    const int wv   = tid >> 6;
    const int wm   = (wv >> 1) * 64;
    const int wn   = (wv & 1) * 64;
    const int lr   = lane & 15;
    const int quad = lane >> 4;
    const int srow   = lane >> 3;
    const int schunk = (lane & 7) ^ srow;
    const int swiz   = lr & 7;

    f32x4 acc[4][4] = {};

    for (int kb = 0; kb < K; kb += BK) {
        #pragma unroll
        for (int s = 0; s < 4; s++) {
            int q = wv * 4 + s;
            int row = q * 8 + srow;
            __builtin_amdgcn_global_load_lds(
                (const __attribute__((address_space(1))) unsigned int*)(Ab + (size_t)row * K + kb + schunk * 8),
                (__attribute__((address_space(3))) unsigned int*)(As + q * 512),
                16, 0, 0);
            __builtin_amdgcn_global_load_lds(
                (const __attribute__((address_space(1))) unsigned int*)(Bb + (size_t)row * K + kb + schunk * 8),
                (__attribute__((address_space(3))) unsigned int*)(Bs + q * 512),
                16, 0, 0);
        }
        __syncthreads();
        #pragma unroll
        for (int kk = 0; kk < BK; kk += 32) {
            bf16x8 af[4], bfr[4];
            const int sc = ((kk >> 3) + quad) ^ swiz;
            #pragma unroll
            for (int i = 0; i < 4; i++)
                af[i] = *reinterpret_cast<const bf16x8*>(&As[(wm + i*16 + lr) * 64 + sc * 8]);
            #pragma unroll
            for (int j = 0; j < 4; j++)
                bfr[j] = *reinterpret_cast<const bf16x8*>(&Bs[(wn + j*16 + lr) * 64 + sc * 8]);
            #pragma unroll
            for (int i = 0; i < 4; i++)
                #pragma unroll
                for (int j = 0; j < 4; j++)
                    acc[i][j] = __builtin_amdgcn_mfma_f32_16x16x32_bf16(af[i], bfr[j], acc[i][j], 0, 0, 0);
        }
        __syncthreads();
    }

    size_t cbase = (size_t)e * M * N + (size_t)bm * BM * N + (size_t)bn * BN;
    float bv[4];
    #pragma unroll
    for (int j = 0; j < 4; j++) bv[j] = bp[bn * BN + wn + j * 16 + lr];
    #pragma unroll
    for (int i = 0; i < 4; i++) {
        #pragma unroll
        for (int rr = 0; rr < 4; rr++) {
            int row = wm + i * 16 + quad * 4 + rr;
            #pragma unroll
            for (int j = 0; j < 4; j++) {
                int col = wn + j * 16 + lr;
                float v = acc[i][j][rr] + bv[j];
                if (GELU) v = 0.5f * v * (1.f + erff(v * 0.70710678118654752440f));
                C[cbase + (size_t)row * N + col] = f2bf(v);
            }
        }
    }
}

// ------------- combine: weighted sum of expert outputs, normalize -------------
__global__ void combine_kernel(const int* __restrict__ topi,
                               const float* __restrict__ topv,
                               const int* __restrict__ pos,
                               const unsigned short* __restrict__ out2,
                               float* __restrict__ y) {
    int t    = blockIdx.x * 4 + (threadIdx.x >> 6);
    int lane = threadIdx.x & 63;
    int e0 = topi[t*2],   e1 = topi[t*2+1];
    float g0 = topv[t*2], g1 = topv[t*2+1];
    int p0 = pos[t*2],    p1 = pos[t*2+1];
    float w0 = (p0 < CAP) ? g0 : 0.f;
    float w1 = (p1 < CAP) ? g1 : 0.f;
    float wsum = w0 + w1;
    float scale = (wsum > 0.f) ? 1.f / fmaxf(wsum, 1e-6f) : 0.f;
    int q0 = p0 < CAP ? p0 : CAP - 1;
    int q1 = p1 < CAP ? p1 : CAP - 1;
    const ushort4* o0 = reinterpret_cast<const ushort4*>(out2 + ((size_t)e0 * CAP + q0) * DMODEL);
    const ushort4* o1 = reinterpret_cast<const ushort4*>(out2 + ((size_t)e1 * CAP + q1) * DMODEL);
    float4* dst = reinterpret_cast<float4*>(y + (size_t)t * DMODEL);
    #pragma unroll
    for (int i = lane; i < DMODEL/4; i += 64) {
        ushort4 a = o0[i], b = o1[i];
        float4 r;
        r.x = (w0 * bf2f(a.x) + w1 * bf2f(b.x)) * scale;
        r.y = (w0 * bf2f(a.y) + w1 * bf2f(b.y)) * scale;
        r.z = (w0 * bf2f(a.z) + w1 * bf2f(b.z)) * scale;
        r.w = (w0 * bf2f(a.w) + w1 * bf2f(b.w)) * scale;
        dst[i] = r;
    }
}

extern "C" void kernel_launch(void* const* d_in, const int* in_sizes, int n_in,
                              void* d_out, int out_size, void* d_ws, size_t ws_size,
                              hipStream_t stream) {
    (void)in_sizes; (void)n_in; (void)out_size; (void)ws_size;
    const float* x        = (const float*)d_in[0];
    const float* w_router = (const float*)d_in[1];
    const float* b_router = (const float*)d_in[2];
    const float* w1       = (const float*)d_in[3];
    const float* b1       = (const float*)d_in[4];
    const float* w2       = (const float*)d_in[5];
    const float* b2       = (const float*)d_in[6];
    float* y = (float*)d_out;

    char* ws = (char*)d_ws;
    size_t off = 0;
    auto alloc = [&](size_t n) { char* p = ws + off; off = (off + n + 255) & ~(size_t)255; return p; };
    int*   topi     = (int*)  alloc((size_t)NASSIGN * 4);
    float* topv     = (float*)alloc((size_t)NASSIGN * 4);
    int*   pos      = (int*)  alloc((size_t)NASSIGN * 4);
    int*   slot_tok = (int*)  alloc((size_t)NEXP * CAP * 4);
    int*   kept     = (int*)  alloc(8 * 4);
    unsigned short* w1t = (unsigned short*)alloc((size_t)NEXP * DMODEL * FFF * 2);
    unsigned short* w2t = (unsigned short*)alloc((size_t)NEXP * DMODEL * FFF * 2);
    unsigned short* xb  = (unsigned short*)alloc((size_t)NEXP * CAP * DMODEL * 2);
    unsigned short* h   = (unsigned short*)alloc((size_t)NEXP * CAP * FFF * 2);
    unsigned short* out2 = w1t;  // alias: w1t is dead after GEMM1

    prologue_kernel<<<NTOK/4 + 16384, 256, 0, stream>>>(
        x, w_router, b_router, w1, w2, topi, topv, w1t, w2t);
    scan_kernel<<<1, 256, 0, stream>>>(topi, pos, slot_tok, kept);
    dispatch_kernel<<<NEXP*CAP/4, 256, 0, stream>>>(x, slot_tok, kept, xb);
    gemm_8p<1><<<dim3((FFF/256)*(CAP/256), 1, NEXP), 512, 0, stream>>>(xb, w1t, b1, h, CAP, FFF, DMODEL);
    gemm_bt<0><<<dim3((DMODEL/128)*(CAP/128), 1, NEXP), 256, 0, stream>>>(h, w2t, b2, out2, CAP, DMODEL, FFF);
    combine_kernel<<<NTOK/4, 256, 0, stream>>>(topi, topv, pos, out2, y);
}